// Round 2
// baseline (1044.492 us; speedup 1.0000x reference)
//
#include <hip/hip_runtime.h>

// 3D neighborhood attention (KS=3) + softmax + expected-offset contraction.
// q,k: (1,64,64,64,96) fp32 ; rpb: (6,3,3,3) fp32 ; out: (1,18,64,64,64) fp32
//
// Round 1 -> 2 changes:
//  * t-strip register blocking: each thread owns TS=4 consecutive t outputs;
//    each loaded k fragment is used for 3 dots (dt=-1,0,1) -> k cache traffic
//    27x -> 13.5x per element.
//  * online accumulation WITHOUT softmax max-pass (logits ~ N(0,1), max ~6,
//    exp safe in fp32) -> only l,a0,a1,a2 per output live, no 27-logit array.
//  * block = (h, 2 adjacent w), 192 threads = 2w x 16 strips x 6 heads.

#define DH 64
#define DW 64
#define DT 64
#define DC 96
#define NH 6
#define HD 16
#define TS 4

__global__ __launch_bounds__(192, 4) void natten3d_kernel(
    const float* __restrict__ q,
    const float* __restrict__ k,
    const float* __restrict__ rpb,
    float* __restrict__ out)
{
    // 2048 blocks, 8 XCDs -> 256 contiguous per XCD (bijective since 2048%8==0)
    int bid = blockIdx.x;
    int nb  = (bid & 7) * 256 + (bid >> 3);
    int h   = nb >> 5;          // nb / 32
    int w2  = nb & 31;          // nb % 32

    int tid = threadIdx.x;
    int wl  = tid / 96;         // which of the 2 w columns
    int rr  = tid - wl * 96;
    int s   = rr / NH;          // strip index 0..15
    int n   = rr - s * NH;      // head 0..5
    int w   = w2 * 2 + wl;
    int t0  = s * TS;

    // ---- q fragments for the strip, pre-scaled by hd^-0.5 = 0.25
    float qv[TS][HD];
    {
        const float* qp = q + ((size_t)((h * DW + w) * DT + t0)) * DC + n * HD;
        #pragma unroll
        for (int u = 0; u < TS; ++u) {
            #pragma unroll
            for (int i = 0; i < HD / 4; ++i) {
                float4 v4 = *reinterpret_cast<const float4*>(qp + u * DC + 4 * i);
                qv[u][4*i+0] = v4.x * 0.25f;
                qv[u][4*i+1] = v4.y * 0.25f;
                qv[u][4*i+2] = v4.z * 0.25f;
                qv[u][4*i+3] = v4.w * 0.25f;
            }
        }
    }

    float l[TS], a0[TS], a1[TS], a2[TS];
    #pragma unroll
    for (int u = 0; u < TS; ++u) { l[u]=0.f; a0[u]=0.f; a1[u]=0.f; a2[u]=0.f; }

    // ---- 9 neighbor columns (di,dj); per column, slide a k window over
    // tt = t0-1 .. t0+TS, each k fragment feeding up to 3 outputs.
    for (int di = 0; di < 3; ++di) {
        int hh = h + di - 1;
        bool hok = (unsigned)hh < DH;
        for (int dj = 0; dj < 3; ++dj) {
            int ww = w + dj - 1;
            bool colok = hok && ((unsigned)ww < DW);
            const float* rp = rpb + ((n * 3 + di) * 3 + dj) * 3;
            float rb0 = rp[0], rb1 = rp[1], rb2 = rp[2];
            float wdi = (float)(di - 1);
            float wdj = (float)(dj - 1);

            #pragma unroll
            for (int j = 0; j < TS + 2; ++j) {
                int tt = t0 + j - 1;
                bool valid = colok && ((unsigned)tt < DT);
                float kf[HD];
                if (valid) {
                    const float* kp = k + ((size_t)((hh * DW + ww) * DT + tt)) * DC + n * HD;
                    #pragma unroll
                    for (int i = 0; i < HD / 4; ++i) {
                        float4 k4 = *reinterpret_cast<const float4*>(kp + 4 * i);
                        kf[4*i+0]=k4.x; kf[4*i+1]=k4.y; kf[4*i+2]=k4.z; kf[4*i+3]=k4.w;
                    }
                } else {
                    #pragma unroll
                    for (int i = 0; i < HD; ++i) kf[i] = 0.f;  // zero-pad semantics
                }
                #pragma unroll
                for (int u = 0; u < TS; ++u) {
                    const int d = j - u;                 // dt index 0..2
                    if (d < 0 || d > 2) continue;        // compile-time prune
                    float dot = 0.f;
                    #pragma unroll
                    for (int i = 0; i < HD; ++i) dot = fmaf(qv[u][i], kf[i], dot);
                    float rb = (d == 0) ? rb0 : (d == 1) ? rb1 : rb2;
                    float p = __expf(dot + rb);          // no max-sub: logits ~N(0,1)
                    l[u] += p;
                    a0[u] = fmaf(p, wdi, a0[u]);
                    a1[u] = fmaf(p, wdj, a1[u]);
                    if (d == 0) a2[u] -= p; else if (d == 2) a2[u] += p;
                }
            }
        }
    }

    // ---- normalize + write: out[(n*3+ax)][h][w][t0..t0+3] as float4
    size_t plane = (size_t)DH * DW * DT;
    size_t sp = (size_t)(h * DW + w) * DT + t0;
    float inv[TS];
    #pragma unroll
    for (int u = 0; u < TS; ++u) inv[u] = 1.f / l[u];

    float4 o0 = { a0[0]*inv[0], a0[1]*inv[1], a0[2]*inv[2], a0[3]*inv[3] };
    float4 o1 = { a1[0]*inv[0], a1[1]*inv[1], a1[2]*inv[2], a1[3]*inv[3] };
    float4 o2 = { a2[0]*inv[0], a2[1]*inv[1], a2[2]*inv[2], a2[3]*inv[3] };
    *reinterpret_cast<float4*>(out + (size_t)(n*3+0)*plane + sp) = o0;
    *reinterpret_cast<float4*>(out + (size_t)(n*3+1)*plane + sp) = o1;
    *reinterpret_cast<float4*>(out + (size_t)(n*3+2)*plane + sp) = o2;
}

extern "C" void kernel_launch(void* const* d_in, const int* in_sizes, int n_in,
                              void* d_out, int out_size, void* d_ws, size_t ws_size,
                              hipStream_t stream) {
    const float* q   = (const float*)d_in[0];
    const float* k   = (const float*)d_in[1];
    const float* rpb = (const float*)d_in[2];
    float* out = (float*)d_out;

    dim3 grid(DH * (DW / 2));   // 2048 blocks: one per (h, w-pair)
    dim3 block(2 * (DT / TS) * NH);  // 192 threads
    hipLaunchKernelGGL(natten3d_kernel, grid, block, 0, stream, q, k, rpb, out);
}

// Round 3
// 562.619 us; speedup vs baseline: 1.8565x; 1.8565x over previous
//
#include <hip/hip_runtime.h>

// 3D neighborhood attention (KS=3) + softmax + expected-offset contraction.
// q,k: (1,64,64,64,96) fp32 ; rpb: (6,3,3,3) fp32 ; out: (1,18,64,64,64) fp32
//
// Round 2 -> 3: round-2's launch_bounds(192,4) capped VGPRs at 64 and spilled
// (WRITE_SIZE 19MB -> 1.8GB). Revert to TS=1 / 384-thread structure (round 1)
// and attack the REAL bottleneck (latency, VALUBusy 15%) with an explicit
// 6-deep rolling fragment pipeline: loads for fragment f+6 issue while
// fragment f computes. Branchless: OOB clamped to a valid address, dot
// select-zeroed (reference zero-pads k, so OOB logit = rpb, still in softmax).

#define DH 64
#define DW 64
#define DT 64
#define DC 96
#define NH 6
#define HD 16
#define DEPTH 6

__global__ __launch_bounds__(384, 2) void natten3d_kernel(
    const float* __restrict__ q,
    const float* __restrict__ k,
    const float* __restrict__ rpb,
    float* __restrict__ out)
{
    // bijective XCD swizzle: 4096 blocks, 8 XCDs, 512 contiguous per XCD
    int bid = blockIdx.x;
    int nb  = (bid & 7) * 512 + (bid >> 3);
    int h = nb >> 6;
    int w = nb & 63;

    int tid = threadIdx.x;
    int t = tid / NH;
    int n = tid - t * NH;

    // ---- q fragment, pre-scaled by hd^-0.5 = 0.25
    const float* qp = q + ((size_t)((h * DW + w) * DT + t)) * DC + n * HD;
    float qv[HD];
    #pragma unroll
    for (int i = 0; i < HD / 4; ++i) {
        float4 v4 = *reinterpret_cast<const float4*>(qp + 4 * i);
        qv[4*i+0] = v4.x * 0.25f;
        qv[4*i+1] = v4.y * 0.25f;
        qv[4*i+2] = v4.z * 0.25f;
        qv[4*i+3] = v4.w * 0.25f;
    }

    // ---- per-column (di,dj) setup: block-uniform -> lives in SGPRs
    int  coff[9];
    bool cok[9];
    #pragma unroll
    for (int c = 0; c < 9; ++c) {
        int di = c / 3, dj = c % 3;
        int hh = h + di - 1, ww = w + dj - 1;
        cok[c] = ((unsigned)hh < DH) && ((unsigned)ww < DW);
        int hc = min(max(hh, 0), DH - 1);
        int wc = min(max(ww, 0), DW - 1);
        coff[c] = (hc * DW + wc) * DT * DC;
    }
    const int tbase = n * HD;
    const bool t_lo_ok = (t > 0);
    const bool t_hi_ok = (t < DT - 1);

    float kb[DEPTH][HD];   // rolling fragment buffer (fully unrolled -> regs)
    float rbv[DEPTH];      // rolling rpb scalar
    float l = 0.f, a0 = 0.f, a1 = 0.f, a2 = 0.f;

    const int rpb_base = n * 27;

    // issue loads for fragment f into slot f%DEPTH (f = c*3 + d, d = dt)
    auto ISSUE = [&](int f) {
        const int c = f / 3, d = f % 3;
        int tt = t + d - 1;
        int ttc = min(max(tt, 0), DT - 1);          // clamp: always-valid addr
        const float* kp = k + (size_t)(coff[c] + ttc * DC + tbase);
        #pragma unroll
        for (int i = 0; i < HD / 4; ++i) {
            float4 k4 = *reinterpret_cast<const float4*>(kp + 4 * i);
            kb[f % DEPTH][4*i+0] = k4.x;
            kb[f % DEPTH][4*i+1] = k4.y;
            kb[f % DEPTH][4*i+2] = k4.z;
            kb[f % DEPTH][4*i+3] = k4.w;
        }
        rbv[f % DEPTH] = rpb[rpb_base + f];
    };

    auto COMPUTE = [&](int f) {
        const int c = f / 3, d = f % 3;
        float d0 = 0.f, d1 = 0.f, d2 = 0.f, d3 = 0.f;
        #pragma unroll
        for (int i = 0; i < HD / 4; ++i) {
            d0 = fmaf(qv[4*i+0], kb[f % DEPTH][4*i+0], d0);
            d1 = fmaf(qv[4*i+1], kb[f % DEPTH][4*i+1], d1);
            d2 = fmaf(qv[4*i+2], kb[f % DEPTH][4*i+2], d2);
            d3 = fmaf(qv[4*i+3], kb[f % DEPTH][4*i+3], d3);
        }
        float dot = (d0 + d1) + (d2 + d3);
        bool valid = cok[c] && (d == 0 ? t_lo_ok : (d == 2 ? t_hi_ok : true));
        dot = valid ? dot : 0.f;                    // zero-pad semantics
        float p = __expf(dot + rbv[f % DEPTH]);     // logits ~N(0,1): no max pass
        l += p;
        // offset weights are compile-time in {-1,0,1}
        if (c / 3 == 0) a0 -= p; else if (c / 3 == 2) a0 += p;
        if (c % 3 == 0) a1 -= p; else if (c % 3 == 2) a1 += p;
        if (d == 0)     a2 -= p; else if (d == 2)     a2 += p;
    };

    // ---- software pipeline: prologue fills DEPTH slots, then compute+issue
    #pragma unroll
    for (int f = 0; f < DEPTH; ++f) ISSUE(f);
    #pragma unroll
    for (int s = 0; s < 27; ++s) {
        COMPUTE(s);
        if (s + DEPTH < 27) ISSUE(s + DEPTH);
    }

    // ---- normalize + write
    float inv = 1.f / l;
    size_t plane = (size_t)DH * DW * DT;
    size_t sp = (size_t)(h * DW + w) * DT + t;
    out[(size_t)(n * 3 + 0) * plane + sp] = a0 * inv;
    out[(size_t)(n * 3 + 1) * plane + sp] = a1 * inv;
    out[(size_t)(n * 3 + 2) * plane + sp] = a2 * inv;
}

extern "C" void kernel_launch(void* const* d_in, const int* in_sizes, int n_in,
                              void* d_out, int out_size, void* d_ws, size_t ws_size,
                              hipStream_t stream) {
    const float* q   = (const float*)d_in[0];
    const float* k   = (const float*)d_in[1];
    const float* rpb = (const float*)d_in[2];
    float* out = (float*)d_out;

    dim3 grid(DH * DW);   // 4096 blocks, one per (h,w)
    dim3 block(DT * NH);  // 384 threads
    hipLaunchKernelGGL(natten3d_kernel, grid, block, 0, stream, q, k, rpb, out);
}

// Round 4
// 323.047 us; speedup vs baseline: 3.2333x; 1.7416x over previous
//
#include <hip/hip_runtime.h>

// 3D neighborhood attention (KS=3) + softmax + expected-offset contraction.
// q,k: (1,64,64,64,96) fp32 ; rpb: (6,3,3,3) fp32 ; out: (1,18,64,64,64) fp32
//
// Round 3 -> 4: rounds 2/3 both died to scratch spills (runtime-indexed
// register arrays). Round-1 baseline (225us) is latency-bound on L1 line
// touches: lanes at 64B stride use 16B per 64B line -> 64 lines touched per
// load instr (27*4*64 = 6912 line-touches/wave ~= 276us model, matches).
// Fix: QUAD-SPLIT the head dim. 4 lanes per (pos,head), 4 channels each:
//   * every k load instr is a dense contiguous 1KB wave read (16 lines, all
//     bytes used) -> 16x fewer line touches (27*16 = 432/wave).
//   * dot reduced across the quad with DPP quad_perm butterflies (pure VALU).
//   * all register arrays constant-indexed inside #pragma unroll (no scratch).

#define DH 64
#define DW 64
#define DT 64
#define DC 96
#define NH 6
#define HD 16

__device__ __forceinline__ float quad_reduce_add(float x) {
    // butterfly across lanes {q, q^1, q^2, q^3} of each aligned quad
    int i = __float_as_int(x);
    i = __builtin_amdgcn_mov_dpp(i, 0xB1, 0xF, 0xF, true);  // quad_perm xor 1
    x += __int_as_float(i);
    i = __float_as_int(x);
    i = __builtin_amdgcn_mov_dpp(i, 0x4E, 0xF, 0xF, true);  // quad_perm xor 2
    x += __int_as_float(i);
    return x;
}

__global__ __launch_bounds__(384) void natten3d_kernel(
    const float* __restrict__ q,
    const float* __restrict__ k,
    const float* __restrict__ rpb,
    float* __restrict__ out)
{
    // 16384 blocks, bijective XCD swizzle (16384 % 8 == 0): 2048/XCD
    int bid = blockIdx.x;
    int nb  = (bid & 7) * 2048 + (bid >> 3);
    int tile = nb & 3;           // t-tile (fastest: tiles of same (h,w) adjacent)
    int w    = (nb >> 2) & 63;
    int h    = nb >> 8;

    int tid  = threadIdx.x;
    int s    = tid & 3;          // channel slice 0..3 (4 channels each)
    int r    = tid >> 2;         // 0..95
    int n    = r % NH;           // head
    int tloc = r / NH;           // 0..15
    int t    = tile * 16 + tloc;

    // ---- q slice (4 channels), pre-scaled by hd^-0.5 = 0.25
    const float* qp = q + ((size_t)((h * DW + w) * DT + t)) * DC + n * HD + s * 4;
    float4 q4 = *reinterpret_cast<const float4*>(qp);
    q4.x *= 0.25f; q4.y *= 0.25f; q4.z *= 0.25f; q4.w *= 0.25f;

    // ---- block-uniform column offsets (element units), clamped; validity flags
    int  coff[9];
    bool cok[9];
    #pragma unroll
    for (int c = 0; c < 9; ++c) {
        int di = c / 3, dj = c % 3;
        int hh = h + di - 1, ww = w + dj - 1;
        cok[c] = ((unsigned)hh < DH) && ((unsigned)ww < DW);
        int hc = min(max(hh, 0), DH - 1);
        int wc = min(max(ww, 0), DW - 1);
        coff[c] = (hc * DW + wc) * DT * DC;
    }

    // ---- per-lane t offsets for dt = 0,1,2 (clamped) + validity
    int  voff[3];
    bool dok[3];
    #pragma unroll
    for (int d = 0; d < 3; ++d) {
        int tt = t + d - 1;
        dok[d] = (unsigned)tt < DT;
        int ttc = min(max(tt, 0), DT - 1);
        voff[d] = ttc * DC + n * HD + s * 4;
    }

    float l = 0.f, a0 = 0.f, a1 = 0.f, a2 = 0.f;
    const int rbase = n * 27;

    #pragma unroll
    for (int g = 0; g < 3; ++g) {          // g == di index; weight wi = g-1
        float4 kb[9];
        float  rb[9];
        // batch-issue 9 dense k loads (+ tiny rpb scalars) -> MLP
        #pragma unroll
        for (int j = 0; j < 9; ++j) {
            const int c = g * 3 + j / 3;   // column index 0..8
            const int d = j % 3;           // dt index
            kb[j] = *reinterpret_cast<const float4*>(k + (size_t)(coff[c] + voff[d]));
            rb[j] = rpb[rbase + g * 9 + j];
        }
        #pragma unroll
        for (int j = 0; j < 9; ++j) {
            const int c = g * 3 + j / 3;
            const int d = j % 3;
            float part = q4.x * kb[j].x;
            part = fmaf(q4.y, kb[j].y, part);
            part = fmaf(q4.z, kb[j].z, part);
            part = fmaf(q4.w, kb[j].w, part);
            part = (cok[c] && dok[d]) ? part : 0.f;   // zero-pad semantics
            float dot = quad_reduce_add(part);         // full 16-ch dot, all 4 lanes
            float p = __expf(dot + rb[j]);             // logits ~N(0,1): no max pass
            l += p;
            // offset weights (compile-time in {-1,0,1})
            if (g == 0)      a0 -= p; else if (g == 2)      a0 += p;
            if (j / 3 == 0)  a1 -= p; else if (j / 3 == 2)  a1 += p;
            if (d == 0)      a2 -= p; else if (d == 2)      a2 += p;
        }
    }

    // ---- normalize + write: lane s<3 of each quad writes axis s
    float inv = 1.f / l;
    float res = ((s == 0) ? a0 : (s == 1) ? a1 : a2) * inv;
    size_t plane = (size_t)DH * DW * DT;
    size_t sp = (size_t)(h * DW + w) * DT + t;
    if (s < 3) out[(size_t)(n * 3 + s) * plane + sp] = res;
}

extern "C" void kernel_launch(void* const* d_in, const int* in_sizes, int n_in,
                              void* d_out, int out_size, void* d_ws, size_t ws_size,
                              hipStream_t stream) {
    const float* q   = (const float*)d_in[0];
    const float* k   = (const float*)d_in[1];
    const float* rpb = (const float*)d_in[2];
    float* out = (float*)d_out;

    dim3 grid(DH * DW * 4);       // 16384 blocks: (h, w, t-tile of 16)
    dim3 block(16 * NH * 4);      // 384 threads = 16 t x 6 heads x 4 slices
    hipLaunchKernelGGL(natten3d_kernel, grid, block, 0, stream, q, k, rpb, out);
}

// Round 5
// 271.320 us; speedup vs baseline: 3.8497x; 1.1906x over previous
//
#include <hip/hip_runtime.h>

// 3D neighborhood attention (KS=3) + softmax + expected-offset contraction.
// q,k: (1,64,64,64,96) fp32 ; rpb: (6,3,3,3) fp32 ; out: (1,18,64,64,64) fp32
//
// Round 4 -> 5:
//  * keep quad-split (4 lanes share one head's 16 channels -> dense 1KB wave
//    loads), ADD t-strip: each quad owns 4 consecutive t outputs. Per column
//    the quad loads 6 k-slices (t-window sharing) instead of 12 -> per-output
//    k loads 27 -> 13.5, line-touches halved, wave count /4.
//  * distribute softmax across the quad: lane s owns output u=s. All 12 (u,d)
//    dots per column are quad-reduced (all lanes' channel partials are needed
//    anyway), each lane keeps its own 3 via cndmask, and exp/accum runs ONCE
//    per output (round 4 did it 4x redundantly; exp is quarter-rate).
//  * everything constant-indexed in full unrolls; no launch_bounds VGPR cap
//    (rounds 2/3 died to spills; gate: WRITE_SIZE must stay ~19 MB).

#define DH 64
#define DW 64
#define DT 64
#define DC 96
#define NH 6
#define HD 16

__device__ __forceinline__ float quad_reduce_add(float x) {
    // butterfly across the 4 lanes of each aligned quad (pure VALU, DPP)
    int i = __float_as_int(x);
    i = __builtin_amdgcn_mov_dpp(i, 0xB1, 0xF, 0xF, true);  // quad_perm xor 1
    x += __int_as_float(i);
    i = __float_as_int(x);
    i = __builtin_amdgcn_mov_dpp(i, 0x4E, 0xF, 0xF, true);  // quad_perm xor 2
    x += __int_as_float(i);
    return x;
}

__global__ __launch_bounds__(384) void natten3d_kernel(
    const float* __restrict__ q,
    const float* __restrict__ k,
    const float* __restrict__ rpb,
    float* __restrict__ out)
{
    // 4096 blocks (one per (h,w)), bijective XCD swizzle: 512 contiguous/XCD
    int bid = blockIdx.x;
    int nb  = (bid & 7) * 512 + (bid >> 3);
    int h = nb >> 6;
    int w = nb & 63;

    int tid  = threadIdx.x;
    int s    = tid & 3;          // quad lane: channel slice AND owned output
    int r    = tid >> 2;         // 0..95
    int n    = r % NH;           // head (fast -> dense wave addresses)
    int t0   = (r / NH) * 4;     // strip base; quad covers t0..t0+3
    int tout = t0 + s;           // the output position this lane owns

    // ---- q fragments for the quad's 4 outputs (lane holds channels 4s..4s+3)
    float4 qv[4];
    {
        const float* qp = q + ((size_t)((h * DW + w) * DT + t0)) * DC + n * HD + s * 4;
        #pragma unroll
        for (int u = 0; u < 4; ++u) {
            float4 v = *reinterpret_cast<const float4*>(qp + u * DC);
            v.x *= 0.25f; v.y *= 0.25f; v.z *= 0.25f; v.w *= 0.25f;  // hd^-0.5
            qv[u] = v;
        }
    }

    // ---- block-uniform neighbor-column offsets (clamped) + validity
    int  coff[9];
    bool cok[9];
    #pragma unroll
    for (int c = 0; c < 9; ++c) {
        int di = c / 3, dj = c % 3;
        int hh = h + di - 1, ww = w + dj - 1;
        cok[c] = ((unsigned)hh < DH) && ((unsigned)ww < DW);
        int hc = min(max(hh, 0), DH - 1);
        int wc = min(max(ww, 0), DW - 1);
        coff[c] = (hc * DW + wc) * DT * DC;
    }

    // ---- per-thread slice offsets, slices j=0..5 <-> tt = t0+j-1 (clamped)
    int soff[6];
    #pragma unroll
    for (int j = 0; j < 6; ++j) {
        int tt = min(max(t0 + j - 1, 0), DT - 1);
        soff[j] = tt * DC + n * HD + s * 4;
    }

    float acc_l = 0.f, acc0 = 0.f, acc1 = 0.f, acc2 = 0.f;
    const int rbase = n * 27;

    #pragma unroll
    for (int c = 0; c < 9; ++c) {
        const int di = c / 3, dj = c % 3;

        // 6 dense k-slices for this column (each: contiguous 1KB wave read)
        float4 kb[6];
        #pragma unroll
        for (int j = 0; j < 6; ++j)
            kb[j] = *reinterpret_cast<const float4*>(k + (size_t)(coff[c] + soff[j]));

        float rb0 = rpb[rbase + c * 3 + 0];
        float rb1 = rpb[rbase + c * 3 + 1];
        float rb2 = rpb[rbase + c * 3 + 2];

        // 12 dots (4 outputs x 3 dt); quad-reduce each; lane keeps its own 3
        float kd0 = 0.f, kd1 = 0.f, kd2 = 0.f;
        #pragma unroll
        for (int u = 0; u < 4; ++u) {
            #pragma unroll
            for (int d = 0; d < 3; ++d) {
                const int j = u + d;                    // compile-time slice
                float p = qv[u].x * kb[j].x;
                p = fmaf(qv[u].y, kb[j].y, p);
                p = fmaf(qv[u].z, kb[j].z, p);
                p = fmaf(qv[u].w, kb[j].w, p);
                float dot = quad_reduce_add(p);         // full 16-ch dot
                const bool mine = (s == u);
                if (d == 0)      kd0 = mine ? dot : kd0;
                else if (d == 1) kd1 = mine ? dot : kd1;
                else             kd2 = mine ? dot : kd2;
            }
        }

        // softmax contribution for the lane's own output only (no redundancy)
        #pragma unroll
        for (int d = 0; d < 3; ++d) {
            float dot = (d == 0) ? kd0 : (d == 1) ? kd1 : kd2;
            bool valid = cok[c] && ((unsigned)(tout + d - 1) < DT);
            float logit = (valid ? dot : 0.f) + ((d == 0) ? rb0 : (d == 1) ? rb1 : rb2);
            float p = __expf(logit);                    // logits ~N(0,1): no max pass
            acc_l += p;
            if (di == 0) acc0 -= p; else if (di == 2) acc0 += p;
            if (dj == 0) acc1 -= p; else if (dj == 2) acc1 += p;
            if (d  == 0) acc2 -= p; else if (d  == 2) acc2 += p;
        }
    }

    // ---- normalize + write: each lane writes its own output position
    float inv = 1.f / acc_l;
    size_t plane = (size_t)DH * DW * DT;
    size_t sp = (size_t)((h * DW + w) * DT) + tout;
    out[(size_t)(n * 3 + 0) * plane + sp] = acc0 * inv;
    out[(size_t)(n * 3 + 1) * plane + sp] = acc1 * inv;
    out[(size_t)(n * 3 + 2) * plane + sp] = acc2 * inv;
}

extern "C" void kernel_launch(void* const* d_in, const int* in_sizes, int n_in,
                              void* d_out, int out_size, void* d_ws, size_t ws_size,
                              hipStream_t stream) {
    const float* q   = (const float*)d_in[0];
    const float* k   = (const float*)d_in[1];
    const float* rpb = (const float*)d_in[2];
    float* out = (float*)d_out;

    dim3 grid(DH * DW);       // 4096 blocks: one (h,w) column each
    dim3 block(16 * NH * 4);  // 384 threads = 16 strips x 6 heads x 4 lanes
    hipLaunchKernelGGL(natten3d_kernel, grid, block, 0, stream, q, k, rpb, out);
}